// Round 4
// baseline (225.083 us; speedup 1.0000x reference)
//
#include <hip/hip_runtime.h>
#include <math.h>

#define B_ 16
#define L_ 256
#define D_ 64

#define CHUNK 32
#define WARM  5
#define NTH   512

#define XPITCH 72                       // padded row: cols -4..67 (zeros outside 0..63)
#define XBUF   (65 * XPITCH)            // x rows -1..63 (index shift +1)
#define HBUF   (62 * XPITCH)            // h rows 0..61 (row 62 never re-read)
#define LDSF   (2 * XBUF + 2 * HBUF)    // 18288 floats = 73 KB

// fast tanh via v_exp_f32: overflow-safe, ~1e-7 rel error (thr 1e-2)
__device__ __forceinline__ float ftanh(float x) {
    float ax = fabsf(x);
    float e  = __builtin_amdgcn_exp2f(-2.8853900818f * ax);   // e^{-2ax}
    float r  = (1.0f - e) * __builtin_amdgcn_rcpf(1.0f + e);
    return copysignf(r, x);
}

// DPP wave shifts with zero boundary fill (bound_ctrl=1)
__device__ __forceinline__ float dpp_shr1(float x) {
    int r = __builtin_amdgcn_update_dpp(0, __float_as_int(x), 0x138, 0xF, 0xF, true);
    return __int_as_float(r);
}
__device__ __forceinline__ float dpp_shl1(float x) {
    int r = __builtin_amdgcn_update_dpp(0, __float_as_int(x), 0x130, 0xF, 0xF, true);
    return __int_as_float(r);
}

// One kernel per layer: block = (b, t-chunk of 32), serial over t with h(t-1)
// rows 0..61 held in double-buffered LDS. 5-step warm-up makes chunk
// boundaries bit-exact (level k at t depends only on levels <k at t-1).
// Row 63 (the truly recurrent row) is handled by scan63 afterwards.
__global__ __launch_bounds__(NTH, 2) void fused_layer(
        const float* __restrict__ X, float* __restrict__ H,
        const float* __restrict__ Wl, const float* __restrict__ bl) {
    __shared__ float lds[LDSF];
    float* const xb0 = lds;
    float* const xb1 = lds + XBUF;
    float* const hb0 = lds + 2 * XBUF;
    float* const hb1 = lds + 2 * XBUF + HBUF;

    const int tid  = threadIdx.x;
    const int b    = blockIdx.x >> 3;            // 8 chunks per batch
    const int ch   = blockIdx.x & 7;
    const int T0   = ch * CHUNK;
    const int tw   = (T0 >= WARM) ? (T0 - WARM) : 0;
    const int tend = T0 + CHUNK;

    // compute-task mapping: threads 0..255 -> rows 0..31 (x-sourced),
    // 256..503 -> rows 32..62 (LDS-sourced), 504..511 idle (stage only)
    const bool lvl0   = tid < 256;
    const bool active = tid < 504;
    const int  idx    = lvl0 ? tid : tid - 256;
    const int  i      = lvl0 ? (idx >> 3) : (32 + (idx >> 3));
    const int  c0     = (idx & 7) << 3;

    float w[9];
#pragma unroll
    for (int k = 0; k < 9; ++k) w[k] = Wl[k];
    const float bias = bl[0];

    // x-staging geometry (all 512 threads: 8 floats each = 16 KB frame)
    const int    srow = tid >> 3;
    const int    scol = (tid & 7) << 3;
    const int    soff = (srow + 1) * XPITCH + 4 + scol;
    const size_t sgl  = (size_t)srow * 64 + scol;

    for (int k = tid; k < LDSF; k += NTH) lds[k] = 0.f;   // pads + h(-1)=0
    __syncthreads();

    {   // stage x(tw) into xb0
        const float* xs = X + (((size_t)(b * L_ + tw)) << 12) + sgl;
        float4 a = reinterpret_cast<const float4*>(xs)[0];
        float4 c = reinterpret_cast<const float4*>(xs)[1];
        float* xd = xb0 + soff;
        reinterpret_cast<float4*>(xd)[0] = a;
        reinterpret_cast<float4*>(xd)[1] = c;
    }
    __syncthreads();

    for (int t = tw; t < tend; ++t) {
        const int cur = (t - tw) & 1;
        float* const xcur        = cur ? xb1 : xb0;
        float* const xnxt        = cur ? xb0 : xb1;
        const float* const hprev = cur ? hb0 : hb1;
        float* const hcur        = cur ? hb1 : hb0;

        // register-prefetch x(t+1) (clamped at sequence end; content unused)
        const int tn = (t + 1 < L_) ? (t + 1) : t;
        const float* xs = X + (((size_t)(b * L_ + tn)) << 12) + sgl;
        const float4 pa = reinterpret_cast<const float4*>(xs)[0];
        const float4 pb = reinterpret_cast<const float4*>(xs)[1];

        if (active) {
            float acc[8];
#pragma unroll
            for (int k = 0; k < 8; ++k) acc[k] = bias;
#pragma unroll
            for (int ki = 0; ki < 3; ++ki) {
                const float* rp;
                if (lvl0) {
                    const int cr = 2 * i - 1 + ki;               // -1..63
                    rp = xcur + (cr + 1) * XPITCH + 4;
                } else {
                    const int rr = 2 * i - 65 + ki;              // -1..61
                    rp = (rr >= 0) ? (hprev + rr * XPITCH + 4)
                                   : (xcur + 64 * XPITCH + 4);   // x row 63
                }
                const float4 v0 = reinterpret_cast<const float4*>(rp + c0 - 4)[0];
                const float4 v1 = reinterpret_cast<const float4*>(rp + c0 - 4)[1];
                const float4 v2 = reinterpret_cast<const float4*>(rp + c0 - 4)[2];
                const float4 v3 = reinterpret_cast<const float4*>(rp + c0 - 4)[3];
                const float g[16] = {v0.x,v0.y,v0.z,v0.w, v1.x,v1.y,v1.z,v1.w,
                                     v2.x,v2.y,v2.z,v2.w, v3.x,v3.y,v3.z,v3.w};
                const float wa = w[ki*3+0], wb = w[ki*3+1], wc = w[ki*3+2];
#pragma unroll
                for (int k = 0; k < 8; ++k)
                    acc[k] = fmaf(wa, g[k+3],
                             fmaf(wb, g[k+4],
                             fmaf(wc, g[k+5], acc[k])));
            }
            float o[8];
#pragma unroll
            for (int k = 0; k < 8; ++k) o[k] = ftanh(acc[k]);

            if (t >= T0) {                                       // skip warm-up
                float* gd = H + (((size_t)(b * L_ + t)) << 12) + i * 64 + c0;
                reinterpret_cast<float4*>(gd)[0] = make_float4(o[0],o[1],o[2],o[3]);
                reinterpret_cast<float4*>(gd)[1] = make_float4(o[4],o[5],o[6],o[7]);
            }
            if (i != 62) {                                       // row 62 not re-read
                float* ld = hcur + i * XPITCH + 4 + c0;
                reinterpret_cast<float4*>(ld)[0] = make_float4(o[0],o[1],o[2],o[3]);
                reinterpret_cast<float4*>(ld)[1] = make_float4(o[4],o[5],o[6],o[7]);
            }
        }
        {   // commit staged x(t+1) into the other x buffer
            float* xd = xnxt + soff;
            reinterpret_cast<float4*>(xd)[0] = pa;
            reinterpret_cast<float4*>(xd)[1] = pb;
        }
        __syncthreads();
    }
}

// Sequential scan for row 63 (reads rows 61/62 from global, written above).
#define SDEPTH 16
__global__ void scan63(float* __restrict__ dst,
                       const float* __restrict__ src,
                       const float* __restrict__ Wl,
                       const float* __restrict__ bl) {
    const int b = blockIdx.x;
    const int j = threadIdx.x;                         // 0..63, one wave
    float w[9];
#pragma unroll
    for (int k = 0; k < 9; ++k) w[k] = Wl[k];
    const float bias = bl[0];

    const size_t ST = (size_t)D_ * D_;
    const float* s61 = src + (size_t)b * L_ * ST + 61 * 64 + j;
    const float* s62 = src + (size_t)b * L_ * ST + 62 * 64 + j;
    float*       d63 = dst + (size_t)b * L_ * ST + 63 * 64 + j;

    float s = ftanh(bias);                             // t=0: h_{-1}=0
    d63[0] = s;

    float p61[SDEPTH], p62[SDEPTH];
#pragma unroll
    for (int u = 0; u < SDEPTH; ++u) {
        p61[u] = s61[(size_t)u * ST];
        p62[u] = s62[(size_t)u * ST];
    }

    for (int t0 = 1; t0 < 256; t0 += SDEPTH) {
#pragma unroll
        for (int u = 0; u < SDEPTH; ++u) {
            const int t = t0 + u;
            if (t > 255) break;
            const float r61 = p61[u], r62 = p62[u];
            int tp = t + SDEPTH - 1;
            if (tp > 255) tp = 255;
            p61[u] = s61[(size_t)tp * ST];
            p62[u] = s62[(size_t)tp * ST];
            float l1 = dpp_shr1(r61), q1 = dpp_shl1(r61);
            float l2 = dpp_shr1(r62), q2 = dpp_shl1(r62);
            float p = bias;
            p = fmaf(w[0], l1, p); p = fmaf(w[1], r61, p); p = fmaf(w[2], q1, p);
            p = fmaf(w[3], l2, p); p = fmaf(w[4], r62, p); p = fmaf(w[5], q2, p);
            float ls = dpp_shr1(s), rs = dpp_shl1(s);
            float z = fmaf(w[6], ls, fmaf(w[7], s, fmaf(w[8], rs, p)));
            s = ftanh(z);
            d63[(size_t)t * ST] = s;
        }
    }
}

extern "C" void kernel_launch(void* const* d_in, const int* in_sizes, int n_in,
                              void* d_out, int out_size, void* d_ws, size_t ws_size,
                              hipStream_t stream) {
    const float* x    = (const float*)d_in[0];   // (B,L,D,D)
    const float* W    = (const float*)d_in[1];   // (2,1,1,3,3)
    const float* bias = (const float*)d_in[2];   // (2,)
    float* out = (float*)d_out;
    float* h1  = (float*)d_ws;

    for (int l = 0; l < 2; ++l) {
        const float* X  = (l == 0) ? x  : h1;
        float*       H  = (l == 0) ? h1 : out;
        fused_layer<<<B_ * (L_ / CHUNK), NTH, 0, stream>>>(X, H, W + l * 9, bias + l);
        scan63<<<B_, 64, 0, stream>>>(H, H, W + l * 9, bias + l);
    }
}

// Round 5
// 148.790 us; speedup vs baseline: 1.5128x; 1.5128x over previous
//
#include <hip/hip_runtime.h>
#include <math.h>

#define B_ 16
#define L_ 256
#define D_ 64

#define CHUNK 16
#define WARM  5
#define NTH   512
#define NCH   (L_ / CHUNK)          // 16 chunks per batch

#define HROWS  63                   // slots 0..62 == concat rows -1..61 (slot0 = x_t row 63)
#define HPITCH 96                   // floats per row = 24 quads(16B); XOR-swizzle closed
#define HBUF   (HROWS * HPITCH)     // 6048 floats
#define LDSF   (2 * HBUF)           // 12096 floats = 47.25 KB

// fast tanh via v_exp_f32: overflow/NaN-safe, ~1e-7 rel error (thr 1e-2)
__device__ __forceinline__ float ftanh(float x) {
    float ax = fabsf(x);
    float e  = __builtin_amdgcn_exp2f(-2.8853900818f * ax);   // e^{-2ax}
    float r  = (1.0f - e) * __builtin_amdgcn_rcpf(1.0f + e);
    return copysignf(r, x);
}

// DPP wave shifts with zero boundary fill (bound_ctrl=1)
__device__ __forceinline__ float dpp_shr1(float x) {
    int r = __builtin_amdgcn_update_dpp(0, __float_as_int(x), 0x138, 0xF, 0xF, true);
    return __int_as_float(r);
}
__device__ __forceinline__ float dpp_shl1(float x) {
    int r = __builtin_amdgcn_update_dpp(0, __float_as_int(x), 0x130, 0xF, 0xF, true);
    return __int_as_float(r);
}

// Per-layer fused kernel. Block = (b, t-chunk of 16), serial over t.
// h(t-1) rows -1..61 live in double-buffered, XOR-swizzled LDS (slot s holds
// concat-prev row s-1; slot 0 = x_t row 63, staged one step ahead by the 8
// spare threads). Rows 0..31 read x straight from global (reg-prefetched).
// 5 warm-up steps make chunk boundaries bit-exact (level k at t depends only
// on levels <k at t-1). Row 63 is finished by scan63.
__global__ __launch_bounds__(NTH, 1) void fused_layer(
        const float* __restrict__ X, float* __restrict__ H,
        const float* __restrict__ Wl, const float* __restrict__ bl) {
    __shared__ float lds[LDSF];
    float* const hA = lds;
    float* const hB = lds + HBUF;

    const int tid  = threadIdx.x;
    const int b    = blockIdx.x >> 4;
    const int ch   = blockIdx.x & (NCH - 1);
    const int T0   = ch * CHUNK;
    const int tw   = (T0 >= WARM) ? (T0 - WARM) : 0;
    const int tend = T0 + CHUNK;

    const bool lvl0 = tid < 256;                  // rows 0..31   (x-sourced)
    const bool comp = tid < 504;                  // + rows 32..62 (LDS-sourced)
    const bool stg  = tid >= 504;                 // x row-63 stagers

    const int idx = lvl0 ? tid : (tid - 256);
    const int i   = lvl0 ? (idx >> 3) : 32 + (idx >> 3);
    const int c0  = (idx & 7) << 3;
    const int c2  = (tid - 504) << 3;             // staging cols (when stg)

    float w[9];
#pragma unroll
    for (int k = 0; k < 9; ++k) w[k] = Wl[k];
    const float bias = bl[0];
    const float4 z4 = make_float4(0.f, 0.f, 0.f, 0.f);

    // zero both h buffers (covers pads, h(-1)=0 for chunk 0; warm-up fixes rest)
    for (int k = tid; k < LDSF / 4; k += NTH) reinterpret_cast<float4*>(lds)[k] = z4;
    __syncthreads();

    // stage x(tw) row 63 into hA slot 0 (slot 0 swizzle v=0: identity)
    if (stg) {
        const float* xs = X + (((size_t)(b * L_ + tw)) << 12) + (63 << 6) + c2;
        *reinterpret_cast<float4*>(hA + c2 + 4) = *reinterpret_cast<const float4*>(xs);
        *reinterpret_cast<float4*>(hA + c2 + 8) = *reinterpret_cast<const float4*>(xs + 4);
    }
    // staging prefetch: x(tw+1) row 63
    float4 p63a = z4, p63b = z4;
    if (stg) {
        const int tn = (tw + 1 < L_) ? tw + 1 : L_ - 1;
        const float* xs = X + (((size_t)(b * L_ + tn)) << 12) + (63 << 6) + c2;
        p63a = *reinterpret_cast<const float4*>(xs);
        p63b = *reinterpret_cast<const float4*>(xs + 4);
    }

    // lvl0: load the 3 tap-row windows (16 floats each) of x(t) into regs
    auto ldx = [&](int t, float4 v[12]) {
        const float* xb = X + (((size_t)(b * L_ + t)) << 12);
#pragma unroll
        for (int ki = 0; ki < 3; ++ki) {
            const int cr = 2 * i - 1 + ki;        // -1..63 (i<32)
            const float* rp = xb + (cr << 6);
            const bool rv = (cr >= 0);
            v[ki*4+0] = (rv && c0 > 0)  ? *reinterpret_cast<const float4*>(rp + c0 - 4) : z4;
            v[ki*4+1] =  rv             ? *reinterpret_cast<const float4*>(rp + c0)     : z4;
            v[ki*4+2] =  rv             ? *reinterpret_cast<const float4*>(rp + c0 + 4) : z4;
            v[ki*4+3] = (rv && c0 < 56) ? *reinterpret_cast<const float4*>(rp + c0 + 8) : z4;
        }
    };
    float4 cx[12];
    if (lvl0) ldx(tw, cx);
    __syncthreads();

    auto STEP = [&](int t, float* hprev, float* hcur) {
        // prefetch x(t+1) windows (lvl0) and x(t+2) row 63 (stg)
        float4 nx[12];
        const int tn = (t + 1 < L_) ? t + 1 : L_ - 1;
        if (lvl0) ldx(tn, nx);
        float4 n63a, n63b;
        if (stg) {
            const int t2 = (t + 2 < L_) ? t + 2 : L_ - 1;
            const float* xs = X + (((size_t)(b * L_ + t2)) << 12) + (63 << 6) + c2;
            n63a = *reinterpret_cast<const float4*>(xs);
            n63b = *reinterpret_cast<const float4*>(xs + 4);
        }
        if (comp) {
            float acc[8];
#pragma unroll
            for (int k = 0; k < 8; ++k) acc[k] = bias;
#pragma unroll
            for (int ki = 0; ki < 3; ++ki) {
                float g[16];
                if (lvl0) {
#pragma unroll
                    for (int k = 0; k < 4; ++k) {
                        g[k*4+0] = cx[ki*4+k].x; g[k*4+1] = cx[ki*4+k].y;
                        g[k*4+2] = cx[ki*4+k].z; g[k*4+3] = cx[ki*4+k].w;
                    }
                } else {
                    const int s  = 2 * i + ki - 64;       // slot 0..62
                    const int v  = (s >> 1) & 7;
                    const float* hb = hprev + s * HPITCH;
                    const int q0 = c0 >> 2;
#pragma unroll
                    for (int k = 0; k < 4; ++k) {
                        const float4 t4 = *reinterpret_cast<const float4*>(
                            hb + (((q0 + k) ^ v) << 2));
                        g[k*4+0] = t4.x; g[k*4+1] = t4.y;
                        g[k*4+2] = t4.z; g[k*4+3] = t4.w;
                    }
                }
                const float wa = w[ki*3], wb = w[ki*3+1], wc = w[ki*3+2];
#pragma unroll
                for (int k = 0; k < 8; ++k)
                    acc[k] = fmaf(wa, g[k+3],
                             fmaf(wb, g[k+4],
                             fmaf(wc, g[k+5], acc[k])));
            }
            float o[8];
#pragma unroll
            for (int k = 0; k < 8; ++k) o[k] = ftanh(acc[k]);

            if (t >= T0) {
                float* gd = H + (((size_t)(b * L_ + t)) << 12) + (i << 6) + c0;
                *reinterpret_cast<float4*>(gd)     = make_float4(o[0],o[1],o[2],o[3]);
                *reinterpret_cast<float4*>(gd + 4) = make_float4(o[4],o[5],o[6],o[7]);
            }
            if (i != 62) {                                // row 62 never re-read
                const int si = i + 1;
                const int vi = (si >> 1) & 7;
                float* hd = hcur + si * HPITCH;
                const int q0 = c0 >> 2;
                *reinterpret_cast<float4*>(hd + (((q0+1) ^ vi) << 2)) =
                    make_float4(o[0],o[1],o[2],o[3]);
                *reinterpret_cast<float4*>(hd + (((q0+2) ^ vi) << 2)) =
                    make_float4(o[4],o[5],o[6],o[7]);
            }
        }
        if (stg) {   // commit x(t+1) row 63 into hcur slot 0 (read next step)
            *reinterpret_cast<float4*>(hcur + c2 + 4) = p63a;
            *reinterpret_cast<float4*>(hcur + c2 + 8) = p63b;
            p63a = n63a; p63b = n63b;
        }
        if (lvl0) {
#pragma unroll
            for (int k = 0; k < 12; ++k) cx[k] = nx[k];
        }
        __syncthreads();
    };

    for (int t = tw; t < tend; t += 2) {          // conditions are block-uniform
        STEP(t, hA, hB);
        if (t + 1 < tend) STEP(t + 1, hB, hA);
    }
}

// Sequential scan for row 63 (reads rows 61/62 from global, written above).
#define SDEPTH 16
__global__ void scan63(float* __restrict__ dst,
                       const float* __restrict__ src,
                       const float* __restrict__ Wl,
                       const float* __restrict__ bl) {
    const int b = blockIdx.x;
    const int j = threadIdx.x;                         // 0..63, one wave
    float w[9];
#pragma unroll
    for (int k = 0; k < 9; ++k) w[k] = Wl[k];
    const float bias = bl[0];

    const size_t ST = (size_t)D_ * D_;
    const float* s61 = src + (size_t)b * L_ * ST + 61 * 64 + j;
    const float* s62 = src + (size_t)b * L_ * ST + 62 * 64 + j;
    float*       d63 = dst + (size_t)b * L_ * ST + 63 * 64 + j;

    float s = ftanh(bias);                             // t=0: h_{-1}=0
    d63[0] = s;

    float p61[SDEPTH], p62[SDEPTH];
#pragma unroll
    for (int u = 0; u < SDEPTH; ++u) {
        p61[u] = s61[(size_t)u * ST];
        p62[u] = s62[(size_t)u * ST];
    }

    for (int t0 = 1; t0 < 256; t0 += SDEPTH) {
#pragma unroll
        for (int u = 0; u < SDEPTH; ++u) {
            const int t = t0 + u;
            if (t > 255) break;
            const float r61 = p61[u], r62 = p62[u];
            int tp = t + SDEPTH - 1;
            if (tp > 255) tp = 255;
            p61[u] = s61[(size_t)tp * ST];
            p62[u] = s62[(size_t)tp * ST];
            float l1 = dpp_shr1(r61), q1 = dpp_shl1(r61);
            float l2 = dpp_shr1(r62), q2 = dpp_shl1(r62);
            float p = bias;
            p = fmaf(w[0], l1, p); p = fmaf(w[1], r61, p); p = fmaf(w[2], q1, p);
            p = fmaf(w[3], l2, p); p = fmaf(w[4], r62, p); p = fmaf(w[5], q2, p);
            float ls = dpp_shr1(s), rs = dpp_shl1(s);
            float z = fmaf(w[6], ls, fmaf(w[7], s, fmaf(w[8], rs, p)));
            s = ftanh(z);
            d63[(size_t)t * ST] = s;
        }
    }
}

extern "C" void kernel_launch(void* const* d_in, const int* in_sizes, int n_in,
                              void* d_out, int out_size, void* d_ws, size_t ws_size,
                              hipStream_t stream) {
    const float* x    = (const float*)d_in[0];   // (B,L,D,D)
    const float* W    = (const float*)d_in[1];   // (2,1,1,3,3)
    const float* bias = (const float*)d_in[2];   // (2,)
    float* out = (float*)d_out;
    float* h1  = (float*)d_ws;

    for (int l = 0; l < 2; ++l) {
        const float* X  = (l == 0) ? x  : h1;
        float*       H  = (l == 0) ? h1 : out;
        fused_layer<<<B_ * NCH, NTH, 0, stream>>>(X, H, W + l * 9, bias + l);
        scan63<<<B_, 64, 0, stream>>>(H, H, W + l * 9, bias + l);
    }
}